// Round 1
// baseline (3445.790 us; speedup 1.0000x reference)
//
#include <hip/hip_runtime.h>
#include <hip/hip_bf16.h>

#define F 128

// ---------------- degree ----------------
__global__ __launch_bounds__(256) void deg_kernel(const int* __restrict__ dst,
                                                  float* __restrict__ deg, int E) {
    int e = blockIdx.x * 256 + threadIdx.x;
    if (e < E) atomicAdd(&deg[dst[e]], 1.0f);
}

__global__ __launch_bounds__(256) void rdeg_kernel(float* __restrict__ deg, int N) {
    int i = blockIdx.x * 256 + threadIdx.x;
    if (i < N) deg[i] = 1.0f / fmaxf(deg[i], 1.0f);
}

// ---------------- aggregate: msg[dst] += h[src], wave per edge ----------------
__global__ __launch_bounds__(256) void agg_kernel(const float* __restrict__ h,
                                                  const int* __restrict__ src,
                                                  const int* __restrict__ dst,
                                                  float* __restrict__ msg, int E) {
    int e = blockIdx.x * 4 + (threadIdx.x >> 6);
    int lane = threadIdx.x & 63;
    if (e >= E) return;
    int s = src[e], d = dst[e];
    float2 v = ((const float2*)(h + (size_t)s * F))[lane];
    float* out = msg + (size_t)d * F;
    atomicAdd(&out[2 * lane + 0], v.x);
    atomicAdd(&out[2 * lane + 1], v.y);
}

// ---------------- fused SAGE layer: out = h@Ws + (msg*rdeg)@Wn + b ----------------
// Block: 256 threads, 16 rows. out may alias msg (rows staged to LDS first).
__global__ __launch_bounds__(256) void sage_layer(const float* __restrict__ h,
                                                  const float* __restrict__ msg,
                                                  const float* __restrict__ rdeg,
                                                  const float* __restrict__ Ws,
                                                  const float* __restrict__ Wn,
                                                  const float* __restrict__ b,
                                                  float* __restrict__ out, int N) {
    __shared__ float hs[16][132];
    __shared__ float ms[16][132];
    int r0 = blockIdx.x * 16;

    for (int i = threadIdx.x; i < 16 * 32; i += 256) {
        int r = i >> 5, c = (i & 31) * 4;
        int row = r0 + r;
        float4 hv = make_float4(0.f, 0.f, 0.f, 0.f);
        float4 mv = make_float4(0.f, 0.f, 0.f, 0.f);
        float rd = 0.f;
        if (row < N) {
            hv = *(const float4*)(h + (size_t)row * F + c);
            mv = *(const float4*)(msg + (size_t)row * F + c);
            rd = rdeg[row];
        }
        *(float4*)&hs[r][c] = hv;
        mv.x *= rd; mv.y *= rd; mv.z *= rd; mv.w *= rd;
        *(float4*)&ms[r][c] = mv;
    }
    __syncthreads();

    int col = threadIdx.x & 127;
    int rb = (threadIdx.x >> 7) * 8;   // rows 0..7 or 8..15
    float bias = b[col];
    float acc[8];
#pragma unroll
    for (int r = 0; r < 8; r++) acc[r] = bias;

    for (int k = 0; k < F; k += 4) {
        float w0s = Ws[(k + 0) * F + col];
        float w1s = Ws[(k + 1) * F + col];
        float w2s = Ws[(k + 2) * F + col];
        float w3s = Ws[(k + 3) * F + col];
        float w0n = Wn[(k + 0) * F + col];
        float w1n = Wn[(k + 1) * F + col];
        float w2n = Wn[(k + 2) * F + col];
        float w3n = Wn[(k + 3) * F + col];
#pragma unroll
        for (int r = 0; r < 8; r++) {
            float4 hv = *(const float4*)&hs[rb + r][k];
            float4 mv = *(const float4*)&ms[rb + r][k];
            acc[r] += hv.x * w0s + hv.y * w1s + hv.z * w2s + hv.w * w3s
                    + mv.x * w0n + mv.y * w1n + mv.z * w2n + mv.w * w3n;
        }
    }

#pragma unroll
    for (int r = 0; r < 8; r++) {
        int row = r0 + rb + r;
        if (row < N) out[(size_t)row * F + col] = acc[r];
    }
}

// ---------------- edge score: s[e] = dot(h[src[e]], h[dst[e]]) ----------------
__global__ __launch_bounds__(256) void edge_score(const float* __restrict__ h,
                                                  const int* __restrict__ src,
                                                  const int* __restrict__ dst,
                                                  float* __restrict__ s, int E) {
    int e = blockIdx.x * 4 + (threadIdx.x >> 6);
    int lane = threadIdx.x & 63;
    if (e >= E) return;
    int si = src[e], di = dst[e];
    float2 a = ((const float2*)(h + (size_t)si * F))[lane];
    float2 b = ((const float2*)(h + (size_t)di * F))[lane];
    float v = a.x * b.x + a.y * b.y;
#pragma unroll
    for (int off = 32; off > 0; off >>= 1) v += __shfl_down(v, off);
    if (lane == 0) s[e] = v;
}

// ---------------- min/max (order-preserving uint encoding) ----------------
__device__ inline unsigned enc_f(float f) {
    unsigned u = __float_as_uint(f);
    return (u & 0x80000000u) ? ~u : (u | 0x80000000u);
}
__device__ inline float dec_f(unsigned u) {
    return (u & 0x80000000u) ? __uint_as_float(u & 0x7FFFFFFFu) : __uint_as_float(~u);
}

__global__ __launch_bounds__(256) void minmax_kernel(const float* __restrict__ s,
                                                     unsigned* __restrict__ mm, int E) {
    float vmin = INFINITY, vmax = -INFINITY;
    for (int i = blockIdx.x * 256 + threadIdx.x; i < E; i += gridDim.x * 256) {
        float v = s[i];
        vmin = fminf(vmin, v);
        vmax = fmaxf(vmax, v);
    }
#pragma unroll
    for (int off = 32; off > 0; off >>= 1) {
        vmin = fminf(vmin, __shfl_down(vmin, off));
        vmax = fmaxf(vmax, __shfl_down(vmax, off));
    }
    __shared__ float smin[4], smax[4];
    int lane = threadIdx.x & 63, wv = threadIdx.x >> 6;
    if (lane == 0) { smin[wv] = vmin; smax[wv] = vmax; }
    __syncthreads();
    if (threadIdx.x == 0) {
        float m = smin[0], M = smax[0];
        for (int w = 1; w < 4; w++) { m = fminf(m, smin[w]); M = fmaxf(M, smax[w]); }
        atomicMin(&mm[0], enc_f(m));
        atomicMax(&mm[1], enc_f(M));
    }
}

__global__ __launch_bounds__(256) void norm_kernel(float* __restrict__ s,
                                                   const unsigned* __restrict__ mm, int E) {
    float mn = dec_f(mm[0]);
    float mx = dec_f(mm[1]);
    float inv = 1.0f / (mx - mn);
    int i = blockIdx.x * 256 + threadIdx.x;
    if (i < E) s[i] = (s[i] - mn) * inv;
}

extern "C" void kernel_launch(void* const* d_in, const int* in_sizes, int n_in,
                              void* d_out, int out_size, void* d_ws, size_t ws_size,
                              hipStream_t stream) {
    const float* x   = (const float*)d_in[0];
    const int*   src = (const int*)d_in[1];
    const int*   dst = (const int*)d_in[2];
    const float* Ws1 = (const float*)d_in[3];
    const float* Wn1 = (const float*)d_in[4];
    const float* b1  = (const float*)d_in[5];
    const float* Ws2 = (const float*)d_in[6];
    const float* Wn2 = (const float*)d_in[7];
    const float* b2  = (const float*)d_in[8];

    int N = in_sizes[0] / F;   // 100000
    int E = in_sizes[1];       // 1600000
    float* out = (float*)d_out;

    float* ws = (float*)d_ws;
    float*    deg = ws;                          // N floats
    unsigned* mm  = (unsigned*)(ws + N);         // 2 words
    float*    A   = ws + 100352;                 // N*F  (msg1 -> msg2 -> h2)
    float*    B   = A + (size_t)N * F;           // N*F  (h1)

    // init scratch (ws is poisoned 0xAA before every call)
    hipMemsetAsync(deg, 0, (size_t)N * sizeof(float), stream);
    hipMemsetAsync(A, 0, (size_t)N * F * sizeof(float), stream);
    hipMemsetAsync(mm, 0xFF, 4, stream);   // min enc = 0xFFFFFFFF
    hipMemsetAsync(mm + 1, 0, 4, stream);  // max enc = 0

    deg_kernel<<<(E + 255) / 256, 256, 0, stream>>>(dst, deg, E);
    rdeg_kernel<<<(N + 255) / 256, 256, 0, stream>>>(deg, N);

    // layer 1
    agg_kernel<<<(E + 3) / 4, 256, 0, stream>>>(x, src, dst, A, E);
    sage_layer<<<(N + 15) / 16, 256, 0, stream>>>(x, A, deg, Ws1, Wn1, b1, B, N);

    // layer 2
    hipMemsetAsync(A, 0, (size_t)N * F * sizeof(float), stream);
    agg_kernel<<<(E + 3) / 4, 256, 0, stream>>>(B, src, dst, A, E);
    sage_layer<<<(N + 15) / 16, 256, 0, stream>>>(B, A, deg, Ws2, Wn2, b2, A, N);

    // edge scores + min-max normalize
    edge_score<<<(E + 3) / 4, 256, 0, stream>>>(A, src, dst, out, E);
    minmax_kernel<<<1024, 256, 0, stream>>>(out, mm, E);
    norm_kernel<<<(E + 255) / 256, 256, 0, stream>>>(out, mm, E);
}

// Round 2
// 1174.172 us; speedup vs baseline: 2.9347x; 2.9347x over previous
//
#include <hip/hip_runtime.h>
#include <hip/hip_bf16.h>

#define F 128

// ---------------- CSR build ----------------
__global__ __launch_bounds__(256) void hist_kernel(const int* __restrict__ dst,
                                                   int* __restrict__ cnt, int E) {
    int e = blockIdx.x * 256 + threadIdx.x;
    if (e < E) atomicAdd(&cnt[dst[e]], 1);
}

// per-block exclusive scan; block totals to bsum
__global__ __launch_bounds__(256) void scan_block(const int* __restrict__ cnt,
                                                  int* __restrict__ off,
                                                  int* __restrict__ bsum, int N) {
    __shared__ int t[256];
    int i = blockIdx.x * 256 + threadIdx.x;
    int v = (i < N) ? cnt[i] : 0;
    t[threadIdx.x] = v;
    __syncthreads();
    for (int o = 1; o < 256; o <<= 1) {
        int x = (threadIdx.x >= o) ? t[threadIdx.x - o] : 0;
        __syncthreads();
        t[threadIdx.x] += x;
        __syncthreads();
    }
    if (i < N) off[i] = t[threadIdx.x] - v;   // exclusive
    if (threadIdx.x == 255) bsum[blockIdx.x] = t[255];
}

// exclusive scan of block sums (nb <= 512) in one block
__global__ __launch_bounds__(512) void scan_sums(int* __restrict__ bsum, int nb) {
    __shared__ int t[512];
    int v = (threadIdx.x < nb) ? bsum[threadIdx.x] : 0;
    t[threadIdx.x] = v;
    __syncthreads();
    for (int o = 1; o < 512; o <<= 1) {
        int x = (threadIdx.x >= o) ? t[threadIdx.x - o] : 0;
        __syncthreads();
        t[threadIdx.x] += x;
        __syncthreads();
    }
    if (threadIdx.x < nb) bsum[threadIdx.x] = t[threadIdx.x] - v;
}

__global__ __launch_bounds__(256) void scan_add(int* __restrict__ off,
                                                const int* __restrict__ bsum, int N) {
    int i = blockIdx.x * 256 + threadIdx.x;
    if (i < N) off[i] += bsum[blockIdx.x];
}

// rdeg from offset diffs; init cursor = offset
__global__ __launch_bounds__(256) void rdeg_cur(const int* __restrict__ off,
                                                float* __restrict__ rdeg,
                                                int* __restrict__ cur, int N, int E) {
    int i = blockIdx.x * 256 + threadIdx.x;
    if (i >= N) return;
    int b = off[i];
    int e = (i == N - 1) ? E : off[i + 1];
    rdeg[i] = 1.0f / fmaxf((float)(e - b), 1.0f);
    cur[i] = b;
}

__global__ __launch_bounds__(256) void scatter_kernel(const int* __restrict__ src,
                                                      const int* __restrict__ dst,
                                                      int* __restrict__ cur,
                                                      int* __restrict__ srcS,
                                                      int* __restrict__ eidS, int E) {
    int e = blockIdx.x * 256 + threadIdx.x;
    if (e >= E) return;
    int d = dst[e];
    int p = atomicAdd(&cur[d], 1);
    srcS[p] = src[e];
    eidS[p] = e;
}

// ---------------- aggregate (gather, no atomics): msg[n] = sum h[srcs of n] ----------------
__global__ __launch_bounds__(256) void agg_gather(const float* __restrict__ h,
                                                  const int* __restrict__ off,
                                                  const int* __restrict__ srcS,
                                                  float* __restrict__ msg, int N, int E) {
    int node = blockIdx.x * 4 + (threadIdx.x >> 6);
    int lane = threadIdx.x & 63;
    if (node >= N) return;
    int p = off[node];
    int pe = (node == N - 1) ? E : off[node + 1];
    float2 acc = make_float2(0.f, 0.f);
    for (; p + 1 < pe; p += 2) {
        int s0 = srcS[p], s1 = srcS[p + 1];
        float2 v0 = ((const float2*)(h + (size_t)s0 * F))[lane];
        float2 v1 = ((const float2*)(h + (size_t)s1 * F))[lane];
        acc.x += v0.x + v1.x;
        acc.y += v0.y + v1.y;
    }
    if (p < pe) {
        int s = srcS[p];
        float2 v = ((const float2*)(h + (size_t)s * F))[lane];
        acc.x += v.x;
        acc.y += v.y;
    }
    ((float2*)(msg + (size_t)node * F))[lane] = acc;
}

// ---------------- fused SAGE layer: out = h@Ws + (msg*rdeg)@Wn + b ----------------
__global__ __launch_bounds__(256) void sage_layer(const float* __restrict__ h,
                                                  const float* __restrict__ msg,
                                                  const float* __restrict__ rdeg,
                                                  const float* __restrict__ Ws,
                                                  const float* __restrict__ Wn,
                                                  const float* __restrict__ b,
                                                  float* __restrict__ out, int N) {
    __shared__ float hs[16][132];
    __shared__ float ms[16][132];
    int r0 = blockIdx.x * 16;

    for (int i = threadIdx.x; i < 16 * 32; i += 256) {
        int r = i >> 5, c = (i & 31) * 4;
        int row = r0 + r;
        float4 hv = make_float4(0.f, 0.f, 0.f, 0.f);
        float4 mv = make_float4(0.f, 0.f, 0.f, 0.f);
        float rd = 0.f;
        if (row < N) {
            hv = *(const float4*)(h + (size_t)row * F + c);
            mv = *(const float4*)(msg + (size_t)row * F + c);
            rd = rdeg[row];
        }
        *(float4*)&hs[r][c] = hv;
        mv.x *= rd; mv.y *= rd; mv.z *= rd; mv.w *= rd;
        *(float4*)&ms[r][c] = mv;
    }
    __syncthreads();

    int col = threadIdx.x & 127;
    int rb = (threadIdx.x >> 7) * 8;
    float bias = b[col];
    float acc[8];
#pragma unroll
    for (int r = 0; r < 8; r++) acc[r] = bias;

    for (int k = 0; k < F; k += 4) {
        float w0s = Ws[(k + 0) * F + col];
        float w1s = Ws[(k + 1) * F + col];
        float w2s = Ws[(k + 2) * F + col];
        float w3s = Ws[(k + 3) * F + col];
        float w0n = Wn[(k + 0) * F + col];
        float w1n = Wn[(k + 1) * F + col];
        float w2n = Wn[(k + 2) * F + col];
        float w3n = Wn[(k + 3) * F + col];
#pragma unroll
        for (int r = 0; r < 8; r++) {
            float4 hv = *(const float4*)&hs[rb + r][k];
            float4 mv = *(const float4*)&ms[rb + r][k];
            acc[r] += hv.x * w0s + hv.y * w1s + hv.z * w2s + hv.w * w3s
                    + mv.x * w0n + mv.y * w1n + mv.z * w2n + mv.w * w3n;
        }
    }

#pragma unroll
    for (int r = 0; r < 8; r++) {
        int row = r0 + rb + r;
        if (row < N) out[(size_t)row * F + col] = acc[r];
    }
}

// ---------------- edge score via CSR: s[eid] = dot(h[src], h[dst]) ----------------
__global__ __launch_bounds__(256) void edge_score_csr(const float* __restrict__ h,
                                                      const int* __restrict__ off,
                                                      const int* __restrict__ srcS,
                                                      const int* __restrict__ eidS,
                                                      float* __restrict__ s, int N, int E) {
    int node = blockIdx.x * 4 + (threadIdx.x >> 6);
    int lane = threadIdx.x & 63;
    if (node >= N) return;
    int p = off[node];
    int pe = (node == N - 1) ? E : off[node + 1];
    if (p >= pe) return;
    float2 d = ((const float2*)(h + (size_t)node * F))[lane];
    for (; p < pe; ++p) {
        int sn = srcS[p];
        int eid = eidS[p];
        float2 a = ((const float2*)(h + (size_t)sn * F))[lane];
        float v = a.x * d.x + a.y * d.y;
#pragma unroll
        for (int o = 32; o > 0; o >>= 1) v += __shfl_down(v, o);
        if (lane == 0) s[eid] = v;
    }
}

// ---------------- min/max + normalize ----------------
__device__ inline unsigned enc_f(float f) {
    unsigned u = __float_as_uint(f);
    return (u & 0x80000000u) ? ~u : (u | 0x80000000u);
}
__device__ inline float dec_f(unsigned u) {
    return (u & 0x80000000u) ? __uint_as_float(u & 0x7FFFFFFFu) : __uint_as_float(~u);
}

__global__ __launch_bounds__(256) void minmax_kernel(const float* __restrict__ s,
                                                     unsigned* __restrict__ mm, int E) {
    float vmin = INFINITY, vmax = -INFINITY;
    for (int i = blockIdx.x * 256 + threadIdx.x; i < E; i += gridDim.x * 256) {
        float v = s[i];
        vmin = fminf(vmin, v);
        vmax = fmaxf(vmax, v);
    }
#pragma unroll
    for (int o = 32; o > 0; o >>= 1) {
        vmin = fminf(vmin, __shfl_down(vmin, o));
        vmax = fmaxf(vmax, __shfl_down(vmax, o));
    }
    __shared__ float smin[4], smax[4];
    int lane = threadIdx.x & 63, wv = threadIdx.x >> 6;
    if (lane == 0) { smin[wv] = vmin; smax[wv] = vmax; }
    __syncthreads();
    if (threadIdx.x == 0) {
        float m = smin[0], M = smax[0];
        for (int w = 1; w < 4; w++) { m = fminf(m, smin[w]); M = fmaxf(M, smax[w]); }
        atomicMin(&mm[0], enc_f(m));
        atomicMax(&mm[1], enc_f(M));
    }
}

__global__ __launch_bounds__(256) void norm_kernel(float* __restrict__ s,
                                                   const unsigned* __restrict__ mm, int E) {
    float mn = dec_f(mm[0]);
    float mx = dec_f(mm[1]);
    float inv = 1.0f / (mx - mn);
    int i = blockIdx.x * 256 + threadIdx.x;
    if (i < E) s[i] = (s[i] - mn) * inv;
}

extern "C" void kernel_launch(void* const* d_in, const int* in_sizes, int n_in,
                              void* d_out, int out_size, void* d_ws, size_t ws_size,
                              hipStream_t stream) {
    const float* x   = (const float*)d_in[0];
    const int*   src = (const int*)d_in[1];
    const int*   dst = (const int*)d_in[2];
    const float* Ws1 = (const float*)d_in[3];
    const float* Wn1 = (const float*)d_in[4];
    const float* b1  = (const float*)d_in[5];
    const float* Ws2 = (const float*)d_in[6];
    const float* Wn2 = (const float*)d_in[7];
    const float* b2  = (const float*)d_in[8];

    int N = in_sizes[0] / F;   // 100000
    int E = in_sizes[1];       // 1600000
    float* out = (float*)d_out;

    // workspace layout (elements of 4 bytes each)
    int* off  = (int*)d_ws;                 // N
    int* cur  = off + N;                    // N
    int* srcS = cur + N;                    // E
    int* eidS = srcS + E;                   // E
    int* bsum = eidS + E;                   // 1024
    float* rdeg = (float*)(bsum + 1024);    // N
    unsigned* mm = (unsigned*)(rdeg + N);   // 2 (+2 pad)
    size_t elemOff = 4 * (size_t)N + 2 * (size_t)E + 1024 + 4;
    elemOff = (elemOff + 3) & ~(size_t)3;   // 16B align for float4
    float* A = (float*)d_ws + elemOff;      // N*F  (msg1 -> msg2 -> h2)
    float* B = A + (size_t)N * F;           // N*F  (h1)

    int nbN = (N + 255) / 256;
    int nbE = (E + 255) / 256;

    // init
    hipMemsetAsync(cur, 0, (size_t)N * sizeof(int), stream);
    hipMemsetAsync(mm, 0xFF, 4, stream);   // min enc
    hipMemsetAsync(mm + 1, 0, 4, stream);  // max enc

    // CSR build (by dst)
    hist_kernel<<<nbE, 256, 0, stream>>>(dst, cur, E);
    scan_block<<<nbN, 256, 0, stream>>>(cur, off, bsum, N);
    scan_sums<<<1, 512, 0, stream>>>(bsum, nbN);
    scan_add<<<nbN, 256, 0, stream>>>(off, bsum, N);
    rdeg_cur<<<nbN, 256, 0, stream>>>(off, rdeg, cur, N, E);
    scatter_kernel<<<nbE, 256, 0, stream>>>(src, dst, cur, srcS, eidS, E);

    // layer 1
    agg_gather<<<(N + 3) / 4, 256, 0, stream>>>(x, off, srcS, A, N, E);
    sage_layer<<<(N + 15) / 16, 256, 0, stream>>>(x, A, rdeg, Ws1, Wn1, b1, B, N);

    // layer 2
    agg_gather<<<(N + 3) / 4, 256, 0, stream>>>(B, off, srcS, A, N, E);
    sage_layer<<<(N + 15) / 16, 256, 0, stream>>>(B, A, rdeg, Ws2, Wn2, b2, A, N);

    // edge scores + min-max normalize
    edge_score_csr<<<(N + 3) / 4, 256, 0, stream>>>(A, off, srcS, eidS, out, N, E);
    minmax_kernel<<<1024, 256, 0, stream>>>(out, mm, E);
    norm_kernel<<<(E + 255) / 256, 256, 0, stream>>>(out, mm, E);
}

// Round 3
// 1001.035 us; speedup vs baseline: 3.4422x; 1.1730x over previous
//
#include <hip/hip_runtime.h>
#include <hip/hip_bf16.h>

#define F 128

typedef unsigned int uint;

// ---------------- CSR build ----------------
__global__ __launch_bounds__(256) void hist_kernel(const int* __restrict__ dst,
                                                   int* __restrict__ cnt, int E) {
    int e = blockIdx.x * 256 + threadIdx.x;
    if (e < E) atomicAdd(&cnt[dst[e]], 1);
}

__global__ __launch_bounds__(256) void scan_block(const int* __restrict__ cnt,
                                                  int* __restrict__ off,
                                                  int* __restrict__ bsum, int N) {
    __shared__ int t[256];
    int i = blockIdx.x * 256 + threadIdx.x;
    int v = (i < N) ? cnt[i] : 0;
    t[threadIdx.x] = v;
    __syncthreads();
    for (int o = 1; o < 256; o <<= 1) {
        int x = (threadIdx.x >= o) ? t[threadIdx.x - o] : 0;
        __syncthreads();
        t[threadIdx.x] += x;
        __syncthreads();
    }
    if (i < N) off[i] = t[threadIdx.x] - v;
    if (threadIdx.x == 255) bsum[blockIdx.x] = t[255];
}

__global__ __launch_bounds__(512) void scan_sums(int* __restrict__ bsum, int nb) {
    __shared__ int t[512];
    int v = (threadIdx.x < nb) ? bsum[threadIdx.x] : 0;
    t[threadIdx.x] = v;
    __syncthreads();
    for (int o = 1; o < 512; o <<= 1) {
        int x = (threadIdx.x >= o) ? t[threadIdx.x - o] : 0;
        __syncthreads();
        t[threadIdx.x] += x;
        __syncthreads();
    }
    if (threadIdx.x < nb) bsum[threadIdx.x] = t[threadIdx.x] - v;
}

__global__ __launch_bounds__(256) void scan_add(int* __restrict__ off,
                                                const int* __restrict__ bsum, int N) {
    int i = blockIdx.x * 256 + threadIdx.x;
    if (i < N) off[i] += bsum[blockIdx.x];
}

__global__ __launch_bounds__(256) void rdeg_cur(const int* __restrict__ off,
                                                float* __restrict__ rdeg,
                                                int* __restrict__ cur, int N, int E) {
    int i = blockIdx.x * 256 + threadIdx.x;
    if (i >= N) return;
    int b = off[i];
    int e = (i == N - 1) ? E : off[i + 1];
    rdeg[i] = 1.0f / fmaxf((float)(e - b), 1.0f);
    cur[i] = b;
}

__global__ __launch_bounds__(256) void scatter_kernel(const int* __restrict__ src,
                                                      const int* __restrict__ dst,
                                                      int* __restrict__ cur,
                                                      int* __restrict__ srcS,
                                                      int* __restrict__ eidS, int E) {
    int e = blockIdx.x * 256 + threadIdx.x;
    if (e >= E) return;
    int d = dst[e];
    int p = atomicAdd(&cur[d], 1);
    srcS[p] = src[e];
    eidS[p] = e;
}

// ---------------- f32 -> bf16 cast (4 elems/thread) ----------------
__global__ __launch_bounds__(256) void cast_bf16(const float* __restrict__ in,
                                                 uint* __restrict__ outb, int n4) {
    int i = blockIdx.x * 256 + threadIdx.x;
    if (i >= n4) return;
    float4 v = ((const float4*)in)[i];
    __hip_bfloat162 a = __float22bfloat162_rn(make_float2(v.x, v.y));
    __hip_bfloat162 b = __float22bfloat162_rn(make_float2(v.z, v.w));
    uint ua, ub;
    __builtin_memcpy(&ua, &a, 4);
    __builtin_memcpy(&ub, &b, 4);
    ((uint2*)outb)[i] = make_uint2(ua, ub);
}

__device__ inline float2 bf2f(uint u) {
    return make_float2(__uint_as_float(u << 16), __uint_as_float(u & 0xFFFF0000u));
}

// ---------------- aggregate (gather, bf16 rows): msg[n] = mean h[srcs] ----------------
// hb row = 64 uints (bf16x2 per lane). Output msg pre-scaled by rdeg (fp32).
__global__ __launch_bounds__(256) void agg_gather(const uint* __restrict__ hb,
                                                  const int* __restrict__ off,
                                                  const int* __restrict__ srcS,
                                                  const float* __restrict__ rdeg,
                                                  float* __restrict__ msg, int N, int E) {
    int node = blockIdx.x * 4 + (threadIdx.x >> 6);
    int lane = threadIdx.x & 63;
    if (node >= N) return;
    int p = off[node];
    int pe = (node == N - 1) ? E : off[node + 1];
    float2 acc = make_float2(0.f, 0.f);
    for (; p + 3 < pe; p += 4) {
        int s0 = srcS[p], s1 = srcS[p + 1], s2 = srcS[p + 2], s3 = srcS[p + 3];
        uint v0 = hb[(size_t)s0 * 64 + lane];
        uint v1 = hb[(size_t)s1 * 64 + lane];
        uint v2 = hb[(size_t)s2 * 64 + lane];
        uint v3 = hb[(size_t)s3 * 64 + lane];
        float2 f0 = bf2f(v0), f1 = bf2f(v1), f2 = bf2f(v2), f3 = bf2f(v3);
        acc.x += (f0.x + f1.x) + (f2.x + f3.x);
        acc.y += (f0.y + f1.y) + (f2.y + f3.y);
    }
    for (; p < pe; ++p) {
        float2 f = bf2f(hb[(size_t)srcS[p] * 64 + lane]);
        acc.x += f.x;
        acc.y += f.y;
    }
    float rd = rdeg[node];
    ((float2*)msg)[(size_t)node * 64 + lane] = make_float2(acc.x * rd, acc.y * rd);
}

// ---------------- fused SAGE layer: out = h@Ws + msg@Wn + b (msg pre-meaned) ----------------
__global__ __launch_bounds__(256) void sage_layer(const float* __restrict__ h,
                                                  const float* __restrict__ msg,
                                                  const float* __restrict__ Ws,
                                                  const float* __restrict__ Wn,
                                                  const float* __restrict__ b,
                                                  float* __restrict__ out, int N) {
    __shared__ float hs[16][132];
    __shared__ float ms[16][132];
    int r0 = blockIdx.x * 16;

    for (int i = threadIdx.x; i < 16 * 32; i += 256) {
        int r = i >> 5, c = (i & 31) * 4;
        int row = r0 + r;
        float4 hv = make_float4(0.f, 0.f, 0.f, 0.f);
        float4 mv = make_float4(0.f, 0.f, 0.f, 0.f);
        if (row < N) {
            hv = *(const float4*)(h + (size_t)row * F + c);
            mv = *(const float4*)(msg + (size_t)row * F + c);
        }
        *(float4*)&hs[r][c] = hv;
        *(float4*)&ms[r][c] = mv;
    }
    __syncthreads();

    int col = threadIdx.x & 127;
    int rb = (threadIdx.x >> 7) * 8;
    float bias = b[col];
    float acc[8];
#pragma unroll
    for (int r = 0; r < 8; r++) acc[r] = bias;

    for (int k = 0; k < F; k += 4) {
        float w0s = Ws[(k + 0) * F + col];
        float w1s = Ws[(k + 1) * F + col];
        float w2s = Ws[(k + 2) * F + col];
        float w3s = Ws[(k + 3) * F + col];
        float w0n = Wn[(k + 0) * F + col];
        float w1n = Wn[(k + 1) * F + col];
        float w2n = Wn[(k + 2) * F + col];
        float w3n = Wn[(k + 3) * F + col];
#pragma unroll
        for (int r = 0; r < 8; r++) {
            float4 hv = *(const float4*)&hs[rb + r][k];
            float4 mv = *(const float4*)&ms[rb + r][k];
            acc[r] += hv.x * w0s + hv.y * w1s + hv.z * w2s + hv.w * w3s
                    + mv.x * w0n + mv.y * w1n + mv.z * w2n + mv.w * w3n;
        }
    }

#pragma unroll
    for (int r = 0; r < 8; r++) {
        int row = r0 + rb + r;
        if (row < N) out[(size_t)row * F + col] = acc[r];
    }
}

// ---------------- edge score via CSR, bf16 rows ----------------
__global__ __launch_bounds__(256) void edge_score_csr(const uint* __restrict__ hb,
                                                      const int* __restrict__ off,
                                                      const int* __restrict__ srcS,
                                                      const int* __restrict__ eidS,
                                                      float* __restrict__ s, int N, int E) {
    int node = blockIdx.x * 4 + (threadIdx.x >> 6);
    int lane = threadIdx.x & 63;
    if (node >= N) return;
    int p = off[node];
    int pe = (node == N - 1) ? E : off[node + 1];
    if (p >= pe) return;
    float2 d = bf2f(hb[(size_t)node * 64 + lane]);
    for (; p + 1 < pe; p += 2) {
        int s0 = srcS[p], s1 = srcS[p + 1];
        int e0 = eidS[p], e1 = eidS[p + 1];
        float2 a0 = bf2f(hb[(size_t)s0 * 64 + lane]);
        float2 a1 = bf2f(hb[(size_t)s1 * 64 + lane]);
        float v0 = a0.x * d.x + a0.y * d.y;
        float v1 = a1.x * d.x + a1.y * d.y;
#pragma unroll
        for (int o = 32; o > 0; o >>= 1) {
            v0 += __shfl_down(v0, o);
            v1 += __shfl_down(v1, o);
        }
        if (lane == 0) { s[e0] = v0; s[e1] = v1; }
    }
    if (p < pe) {
        float2 a = bf2f(hb[(size_t)srcS[p] * 64 + lane]);
        float v = a.x * d.x + a.y * d.y;
#pragma unroll
        for (int o = 32; o > 0; o >>= 1) v += __shfl_down(v, o);
        if (lane == 0) s[eidS[p]] = v;
    }
}

// ---------------- min/max + normalize ----------------
__device__ inline unsigned enc_f(float f) {
    unsigned u = __float_as_uint(f);
    return (u & 0x80000000u) ? ~u : (u | 0x80000000u);
}
__device__ inline float dec_f(unsigned u) {
    return (u & 0x80000000u) ? __uint_as_float(u & 0x7FFFFFFFu) : __uint_as_float(~u);
}

__global__ __launch_bounds__(256) void minmax_kernel(const float* __restrict__ s,
                                                     unsigned* __restrict__ mm, int E) {
    float vmin = INFINITY, vmax = -INFINITY;
    for (int i = blockIdx.x * 256 + threadIdx.x; i < E; i += gridDim.x * 256) {
        float v = s[i];
        vmin = fminf(vmin, v);
        vmax = fmaxf(vmax, v);
    }
#pragma unroll
    for (int o = 32; o > 0; o >>= 1) {
        vmin = fminf(vmin, __shfl_down(vmin, o));
        vmax = fmaxf(vmax, __shfl_down(vmax, o));
    }
    __shared__ float smin[4], smax[4];
    int lane = threadIdx.x & 63, wv = threadIdx.x >> 6;
    if (lane == 0) { smin[wv] = vmin; smax[wv] = vmax; }
    __syncthreads();
    if (threadIdx.x == 0) {
        float m = smin[0], M = smax[0];
        for (int w = 1; w < 4; w++) { m = fminf(m, smin[w]); M = fmaxf(M, smax[w]); }
        atomicMin(&mm[0], enc_f(m));
        atomicMax(&mm[1], enc_f(M));
    }
}

__global__ __launch_bounds__(256) void norm_kernel(float* __restrict__ s,
                                                   const unsigned* __restrict__ mm, int E) {
    float mn = dec_f(mm[0]);
    float mx = dec_f(mm[1]);
    float inv = 1.0f / (mx - mn);
    int i = blockIdx.x * 256 + threadIdx.x;
    if (i < E) s[i] = (s[i] - mn) * inv;
}

extern "C" void kernel_launch(void* const* d_in, const int* in_sizes, int n_in,
                              void* d_out, int out_size, void* d_ws, size_t ws_size,
                              hipStream_t stream) {
    const float* x   = (const float*)d_in[0];
    const int*   src = (const int*)d_in[1];
    const int*   dst = (const int*)d_in[2];
    const float* Ws1 = (const float*)d_in[3];
    const float* Wn1 = (const float*)d_in[4];
    const float* b1  = (const float*)d_in[5];
    const float* Ws2 = (const float*)d_in[6];
    const float* Wn2 = (const float*)d_in[7];
    const float* b2  = (const float*)d_in[8];

    int N = in_sizes[0] / F;   // 100000
    int E = in_sizes[1];       // 1600000
    float* out = (float*)d_out;

    // workspace layout (4-byte elements)
    int* off  = (int*)d_ws;                 // N
    int* cur  = off + N;                    // N
    int* srcS = cur + N;                    // E
    int* eidS = srcS + E;                   // E
    int* bsum = eidS + E;                   // 1024
    float* rdeg = (float*)(bsum + 1024);    // N
    unsigned* mm = (unsigned*)(rdeg + N);   // 2 (+2 pad)
    size_t elemOff = 4 * (size_t)N + 2 * (size_t)E + 1024 + 4;
    elemOff = (elemOff + 3) & ~(size_t)3;   // 16B align
    float* A = (float*)d_ws + elemOff;      // N*F  (msg1 -> msg2 -> h2)
    float* B = A + (size_t)N * F;           // N*F  (h1)
    uint* bfbuf = (uint*)(B + (size_t)N * F); // N*F/2 words (bf16 rows, reused)

    int nbN = (N + 255) / 256;
    int nbE = (E + 255) / 256;
    int NF4 = N * F / 4;

    // init
    hipMemsetAsync(cur, 0, (size_t)N * sizeof(int), stream);
    hipMemsetAsync(mm, 0xFF, 4, stream);   // min enc
    hipMemsetAsync(mm + 1, 0, 4, stream);  // max enc

    // CSR build (by dst)
    hist_kernel<<<nbE, 256, 0, stream>>>(dst, cur, E);
    scan_block<<<nbN, 256, 0, stream>>>(cur, off, bsum, N);
    scan_sums<<<1, 512, 0, stream>>>(bsum, nbN);
    scan_add<<<nbN, 256, 0, stream>>>(off, bsum, N);
    rdeg_cur<<<nbN, 256, 0, stream>>>(off, rdeg, cur, N, E);
    scatter_kernel<<<nbE, 256, 0, stream>>>(src, dst, cur, srcS, eidS, E);

    // layer 1
    cast_bf16<<<(NF4 + 255) / 256, 256, 0, stream>>>(x, bfbuf, NF4);
    agg_gather<<<(N + 3) / 4, 256, 0, stream>>>(bfbuf, off, srcS, rdeg, A, N, E);
    sage_layer<<<(N + 15) / 16, 256, 0, stream>>>(x, A, Ws1, Wn1, b1, B, N);

    // layer 2
    cast_bf16<<<(NF4 + 255) / 256, 256, 0, stream>>>(B, bfbuf, NF4);
    agg_gather<<<(N + 3) / 4, 256, 0, stream>>>(bfbuf, off, srcS, rdeg, A, N, E);
    sage_layer<<<(N + 15) / 16, 256, 0, stream>>>(B, A, Ws2, Wn2, b2, A, N);

    // edge scores + min-max normalize
    cast_bf16<<<(NF4 + 255) / 256, 256, 0, stream>>>(A, bfbuf, NF4);
    edge_score_csr<<<(N + 3) / 4, 256, 0, stream>>>(bfbuf, off, srcS, eidS, out, N, E);
    minmax_kernel<<<1024, 256, 0, stream>>>(out, mm, E);
    norm_kernel<<<(E + 255) / 256, 256, 0, stream>>>(out, mm, E);
}

// Round 4
// 811.096 us; speedup vs baseline: 4.2483x; 1.2342x over previous
//
#include <hip/hip_runtime.h>
#include <hip/hip_bf16.h>

#define F 128

typedef unsigned int uint;
typedef unsigned short ushort;
typedef __attribute__((ext_vector_type(8))) short short8;   // 8 bf16
typedef __attribute__((ext_vector_type(4))) float f32x4;

__device__ inline ushort f2bf(float f) {
    uint u = __float_as_uint(f);
    u += 0x7FFF + ((u >> 16) & 1);   // round-to-nearest-even
    return (ushort)(u >> 16);
}
__device__ inline float2 bf2f(uint u) {
    return make_float2(__uint_as_float(u << 16), __uint_as_float(u & 0xFFFF0000u));
}

// ---------------- CSR build ----------------
__global__ __launch_bounds__(256) void hist_kernel(const int* __restrict__ dst,
                                                   int* __restrict__ cnt, int E) {
    int e = blockIdx.x * 256 + threadIdx.x;
    if (e < E) atomicAdd(&cnt[dst[e]], 1);
}

__global__ __launch_bounds__(256) void scan_block(const int* __restrict__ cnt,
                                                  int* __restrict__ off,
                                                  int* __restrict__ bsum, int N) {
    __shared__ int t[256];
    int i = blockIdx.x * 256 + threadIdx.x;
    int v = (i < N) ? cnt[i] : 0;
    t[threadIdx.x] = v;
    __syncthreads();
    for (int o = 1; o < 256; o <<= 1) {
        int x = (threadIdx.x >= o) ? t[threadIdx.x - o] : 0;
        __syncthreads();
        t[threadIdx.x] += x;
        __syncthreads();
    }
    if (i < N) off[i] = t[threadIdx.x] - v;
    if (threadIdx.x == 255) bsum[blockIdx.x] = t[255];
}

__global__ __launch_bounds__(512) void scan_sums(int* __restrict__ bsum, int nb) {
    __shared__ int t[512];
    int v = (threadIdx.x < nb) ? bsum[threadIdx.x] : 0;
    t[threadIdx.x] = v;
    __syncthreads();
    for (int o = 1; o < 512; o <<= 1) {
        int x = (threadIdx.x >= o) ? t[threadIdx.x - o] : 0;
        __syncthreads();
        t[threadIdx.x] += x;
        __syncthreads();
    }
    if (threadIdx.x < nb) bsum[threadIdx.x] = t[threadIdx.x] - v;
}

__global__ __launch_bounds__(256) void scan_add(int* __restrict__ off,
                                                const int* __restrict__ bsum, int N) {
    int i = blockIdx.x * 256 + threadIdx.x;
    if (i < N) off[i] += bsum[blockIdx.x];
}

__global__ __launch_bounds__(256) void rdeg_cur(const int* __restrict__ off,
                                                float* __restrict__ rdeg,
                                                int* __restrict__ cur, int N, int E) {
    int i = blockIdx.x * 256 + threadIdx.x;
    if (i >= N) return;
    int b = off[i];
    int e = (i == N - 1) ? E : off[i + 1];
    rdeg[i] = 1.0f / fmaxf((float)(e - b), 1.0f);
    cur[i] = b;
}

__global__ __launch_bounds__(256) void scatter_kernel(const int* __restrict__ src,
                                                      const int* __restrict__ dst,
                                                      int* __restrict__ cur,
                                                      int* __restrict__ srcS,
                                                      int* __restrict__ eidS, int E) {
    int e = blockIdx.x * 256 + threadIdx.x;
    if (e >= E) return;
    int d = dst[e];
    int p = atomicAdd(&cur[d], 1);
    srcS[p] = src[e];
    eidS[p] = e;
}

// ---------------- weight prep: cast + transpose 4 matrices [k][n] -> bf16 [n][k] ----------------
__global__ __launch_bounds__(256) void wprep(const float* __restrict__ W0,
                                             const float* __restrict__ W1,
                                             const float* __restrict__ W2,
                                             const float* __restrict__ W3,
                                             ushort* __restrict__ Wt) {
    int idx = blockIdx.x * 256 + threadIdx.x;   // 4 * 128*128
    if (idx >= 4 * 16384) return;
    int mat = idx >> 14;
    int pos = idx & 16383;
    int k = pos >> 7, n = pos & 127;
    const float* W = (mat == 0) ? W0 : (mat == 1) ? W1 : (mat == 2) ? W2 : W3;
    Wt[mat * 16384 + n * 128 + k] = f2bf(W[k * 128 + n]);
}

// ---------------- f32 -> bf16 cast (x only) ----------------
__global__ __launch_bounds__(256) void cast_bf16(const float* __restrict__ in,
                                                 uint* __restrict__ outb, int n4) {
    int i = blockIdx.x * 256 + threadIdx.x;
    if (i >= n4) return;
    float4 v = ((const float4*)in)[i];
    uint ua = (uint)f2bf(v.x) | ((uint)f2bf(v.y) << 16);
    uint ub = (uint)f2bf(v.z) | ((uint)f2bf(v.w) << 16);
    ((uint2*)outb)[i] = make_uint2(ua, ub);
}

// ---------------- aggregate (gather, bf16 in, bf16 out): msg[n] = mean h[srcs] ----------------
__global__ __launch_bounds__(256) void agg_gather(const uint* __restrict__ hb,
                                                  const int* __restrict__ off,
                                                  const int* __restrict__ srcS,
                                                  const float* __restrict__ rdeg,
                                                  uint* __restrict__ msgb, int N, int E) {
    int node = blockIdx.x * 4 + (threadIdx.x >> 6);
    int lane = threadIdx.x & 63;
    if (node >= N) return;
    int p = off[node];
    int pe = (node == N - 1) ? E : off[node + 1];
    float2 acc = make_float2(0.f, 0.f);
    for (; p + 3 < pe; p += 4) {
        int s0 = srcS[p], s1 = srcS[p + 1], s2 = srcS[p + 2], s3 = srcS[p + 3];
        float2 f0 = bf2f(hb[(size_t)s0 * 64 + lane]);
        float2 f1 = bf2f(hb[(size_t)s1 * 64 + lane]);
        float2 f2 = bf2f(hb[(size_t)s2 * 64 + lane]);
        float2 f3 = bf2f(hb[(size_t)s3 * 64 + lane]);
        acc.x += (f0.x + f1.x) + (f2.x + f3.x);
        acc.y += (f0.y + f1.y) + (f2.y + f3.y);
    }
    for (; p < pe; ++p) {
        float2 f = bf2f(hb[(size_t)srcS[p] * 64 + lane]);
        acc.x += f.x;
        acc.y += f.y;
    }
    float rd = rdeg[node];
    uint pk = (uint)f2bf(acc.x * rd) | ((uint)f2bf(acc.y * rd) << 16);
    msgb[(size_t)node * 64 + lane] = pk;
}

// ---------------- SAGE layer via MFMA: outb = bf16(hb@Ws + msgb@Wn + b) ----------------
// Block 256 thr = 4 waves, 64 rows/block; wave: 16 rows x 128 cols, K=256 (hb|msgb).
// Wt layout: [sel][n=128][k=128] bf16, sel0=Ws^T, sel1=Wn^T.
__global__ __launch_bounds__(256) void sage_mfma(const uint* __restrict__ hb,
                                                 const uint* __restrict__ mb,
                                                 const uint* __restrict__ Wt,
                                                 const float* __restrict__ bias,
                                                 ushort* __restrict__ outb, int N) {
    int wave = threadIdx.x >> 6, lane = threadIdx.x & 63;
    int m = lane & 15, q = lane >> 4;
    int r0 = blockIdx.x * 64 + wave * 16;
    int arow = r0 + m;
    if (arow >= N) arow = N - 1;          // clamp: only affects masked-out C rows

    f32x4 acc[8];
#pragma unroll
    for (int t = 0; t < 8; t++) acc[t] = (f32x4){0.f, 0.f, 0.f, 0.f};

    const uint* hrow = hb + (size_t)arow * 64;
    const uint* mrow = mb + (size_t)arow * 64;
#pragma unroll
    for (int sel = 0; sel < 2; sel++) {
        const uint* arowp = sel ? mrow : hrow;
        const uint* wsel = Wt + sel * 8192;
#pragma unroll
        for (int kk = 0; kk < 4; kk++) {
            int ko = kk * 16 + q * 4;     // uint offset: covers bf16 k = kk*32 + q*8 .. +7
            short8 a = *(const short8*)(arowp + ko);
#pragma unroll
            for (int t = 0; t < 8; t++) {
                short8 b = *(const short8*)(wsel + (size_t)(16 * t + m) * 64 + ko);
                acc[t] = __builtin_amdgcn_mfma_f32_16x16x32_bf16(a, b, acc[t], 0, 0, 0);
            }
        }
    }

#pragma unroll
    for (int t = 0; t < 8; t++) {
        float bs = bias[16 * t + m];      // C: col = lane&15 (+16t), row = q*4 + reg
#pragma unroll
        for (int r = 0; r < 4; r++) {
            int orow = r0 + q * 4 + r;
            if (orow < N) outb[(size_t)orow * 128 + 16 * t + m] = f2bf(acc[t][r] + bs);
        }
    }
}

// ---------------- edge score via CSR, bf16 rows ----------------
__global__ __launch_bounds__(256) void edge_score_csr(const uint* __restrict__ hb,
                                                      const int* __restrict__ off,
                                                      const int* __restrict__ srcS,
                                                      const int* __restrict__ eidS,
                                                      float* __restrict__ s, int N, int E) {
    int node = blockIdx.x * 4 + (threadIdx.x >> 6);
    int lane = threadIdx.x & 63;
    if (node >= N) return;
    int p = off[node];
    int pe = (node == N - 1) ? E : off[node + 1];
    if (p >= pe) return;
    float2 d = bf2f(hb[(size_t)node * 64 + lane]);
    for (; p + 1 < pe; p += 2) {
        int s0 = srcS[p], s1 = srcS[p + 1];
        int e0 = eidS[p], e1 = eidS[p + 1];
        float2 a0 = bf2f(hb[(size_t)s0 * 64 + lane]);
        float2 a1 = bf2f(hb[(size_t)s1 * 64 + lane]);
        float v0 = a0.x * d.x + a0.y * d.y;
        float v1 = a1.x * d.x + a1.y * d.y;
#pragma unroll
        for (int o = 32; o > 0; o >>= 1) {
            v0 += __shfl_down(v0, o);
            v1 += __shfl_down(v1, o);
        }
        if (lane == 0) { s[e0] = v0; s[e1] = v1; }
    }
    if (p < pe) {
        float2 a = bf2f(hb[(size_t)srcS[p] * 64 + lane]);
        float v = a.x * d.x + a.y * d.y;
#pragma unroll
        for (int o = 32; o > 0; o >>= 1) v += __shfl_down(v, o);
        if (lane == 0) s[eidS[p]] = v;
    }
}

// ---------------- min/max + normalize ----------------
__device__ inline unsigned enc_f(float f) {
    unsigned u = __float_as_uint(f);
    return (u & 0x80000000u) ? ~u : (u | 0x80000000u);
}
__device__ inline float dec_f(unsigned u) {
    return (u & 0x80000000u) ? __uint_as_float(u & 0x7FFFFFFFu) : __uint_as_float(~u);
}

__global__ __launch_bounds__(256) void minmax_kernel(const float* __restrict__ s,
                                                     unsigned* __restrict__ mm, int E) {
    float vmin = INFINITY, vmax = -INFINITY;
    for (int i = blockIdx.x * 256 + threadIdx.x; i < E; i += gridDim.x * 256) {
        float v = s[i];
        vmin = fminf(vmin, v);
        vmax = fmaxf(vmax, v);
    }
#pragma unroll
    for (int o = 32; o > 0; o >>= 1) {
        vmin = fminf(vmin, __shfl_down(vmin, o));
        vmax = fmaxf(vmax, __shfl_down(vmax, o));
    }
    __shared__ float smin[4], smax[4];
    int lane = threadIdx.x & 63, wv = threadIdx.x >> 6;
    if (lane == 0) { smin[wv] = vmin; smax[wv] = vmax; }
    __syncthreads();
    if (threadIdx.x == 0) {
        float m = smin[0], M = smax[0];
        for (int w = 1; w < 4; w++) { m = fminf(m, smin[w]); M = fmaxf(M, smax[w]); }
        atomicMin(&mm[0], enc_f(m));
        atomicMax(&mm[1], enc_f(M));
    }
}

__global__ __launch_bounds__(256) void norm_kernel(float* __restrict__ s,
                                                   const unsigned* __restrict__ mm, int E) {
    float mn = dec_f(mm[0]);
    float mx = dec_f(mm[1]);
    float inv = 1.0f / (mx - mn);
    int i = blockIdx.x * 256 + threadIdx.x;
    if (i < E) s[i] = (s[i] - mn) * inv;
}

extern "C" void kernel_launch(void* const* d_in, const int* in_sizes, int n_in,
                              void* d_out, int out_size, void* d_ws, size_t ws_size,
                              hipStream_t stream) {
    const float* x   = (const float*)d_in[0];
    const int*   src = (const int*)d_in[1];
    const int*   dst = (const int*)d_in[2];
    const float* Ws1 = (const float*)d_in[3];
    const float* Wn1 = (const float*)d_in[4];
    const float* b1  = (const float*)d_in[5];
    const float* Ws2 = (const float*)d_in[6];
    const float* Wn2 = (const float*)d_in[7];
    const float* b2  = (const float*)d_in[8];

    int N = in_sizes[0] / F;   // 100000
    int E = in_sizes[1];       // 1600000
    float* out = (float*)d_out;

    // workspace layout (4-byte elements)
    int* off  = (int*)d_ws;                  // N
    int* cur  = off + N;                     // N
    int* srcS = cur + N;                     // E
    int* eidS = srcS + E;                    // E
    int* bsum = eidS + E;                    // 1024
    float* rdeg = (float*)(bsum + 1024);     // N
    unsigned* mm = (unsigned*)(rdeg + N);    // 4 (2 used)
    uint* Wtb = (uint*)(mm + 4);             // 4*16384 bf16 = 32768 uints
    uint* xb   = Wtb + 32768;                // N*64
    uint* msgb = xb + (size_t)N * 64;        // N*64
    uint* h1b  = msgb + (size_t)N * 64;      // N*64
    uint* h2b  = h1b + (size_t)N * 64;       // N*64

    int nbN = (N + 255) / 256;
    int nbE = (E + 255) / 256;
    int NF4 = N * F / 4;

    // init
    hipMemsetAsync(cur, 0, (size_t)N * sizeof(int), stream);
    hipMemsetAsync(mm, 0xFF, 4, stream);   // min enc
    hipMemsetAsync(mm + 1, 0, 4, stream);  // max enc

    // CSR build (by dst)
    hist_kernel<<<nbE, 256, 0, stream>>>(dst, cur, E);
    scan_block<<<nbN, 256, 0, stream>>>(cur, off, bsum, N);
    scan_sums<<<1, 512, 0, stream>>>(bsum, nbN);
    scan_add<<<nbN, 256, 0, stream>>>(off, bsum, N);
    rdeg_cur<<<nbN, 256, 0, stream>>>(off, rdeg, cur, N, E);
    scatter_kernel<<<nbE, 256, 0, stream>>>(src, dst, cur, srcS, eidS, E);

    // weights + input cast
    wprep<<<256, 256, 0, stream>>>(Ws1, Wn1, Ws2, Wn2, (ushort*)Wtb);
    cast_bf16<<<(NF4 + 255) / 256, 256, 0, stream>>>(x, xb, NF4);

    // layer 1
    agg_gather<<<(N + 3) / 4, 256, 0, stream>>>(xb, off, srcS, rdeg, msgb, N, E);
    sage_mfma<<<(N + 63) / 64, 256, 0, stream>>>(xb, msgb, Wtb, b1, (ushort*)h1b, N);

    // layer 2
    agg_gather<<<(N + 3) / 4, 256, 0, stream>>>(h1b, off, srcS, rdeg, msgb, N, E);
    sage_mfma<<<(N + 63) / 64, 256, 0, stream>>>(h1b, msgb, Wtb + 16384, b2, (ushort*)h2b, N);

    // edge scores + min-max normalize
    edge_score_csr<<<(N + 3) / 4, 256, 0, stream>>>(h2b, off, srcS, eidS, out, N, E);
    minmax_kernel<<<1024, 256, 0, stream>>>(out, mm, E);
    norm_kernel<<<(E + 255) / 256, 256, 0, stream>>>(out, mm, E);
}